// Round 5
// baseline (314.728 us; speedup 1.0000x reference)
//
#include <hip/hip_runtime.h>
#include <hip/hip_bf16.h>

// GCN forward, MI355X. Round 5: fused pipeline.
//   memset(deg), memset(pooled+cnt)
//   cvt_we   : weights -> bf16 canonical (W1..W4 fragment-major) | batch->i32
//              | edges->i32 + degree count    (per-block inline dtype detect)
//   scan1    : per-block degree totals
//   scan23   : block scan + partial-reduce -> row_ptr / cursor / dinv
//   fill     : packed uint2 CSR (src, coef)
//   gemm1    : X @ W1 via MFMA, A-frags straight from raw x (fp32 or bf16)
//   agg_gemm<128,64>, <64,32>, <32,16> : gather(prev H)+self+bias+relu -> LDS
//              tile -> MFMA next layer  (no xcan round-trip)
//   agg_pool : gather last layer + relu -> LDS graph accumulate -> atomics
//   final    : 64x16 @ 16x10 linear, dtype-dispatched store
//
// MFMA 16x16x32_bf16 layouts (verified): A[m=l&15][k=(l>>4)*8+j] (k-contig);
// B frag f at Wf[f*1024 + l*16..+16] = B[kb*32+(l>>4)*8+j][ct*16+(l&15)],
// f=ct*KB+kb; C/D col=l&15, row=(l>>4)*4+reg.

#define N_GRAPHS 64
#define N_CLASSES 10

typedef short bf8_t __attribute__((ext_vector_type(8)));
typedef float f4_t  __attribute__((ext_vector_type(4)));

__device__ __forceinline__ float b2f(unsigned int u) {
  return __uint_as_float(u << 16);
}
__device__ __forceinline__ unsigned short f2b(float f) {
  unsigned int x = __float_as_uint(f);
  x += 0x7fffu + ((x >> 16) & 1u);   // RNE (finite values only)
  return (unsigned short)(x >> 16);
}

// Per-block dtype detect. Must be called by all 256 threads pre-divergence.
// f32: low-16 bf16-exponent of first 256 x dwords clusters in [100,140] only
// when buffer is packed bf16. i64: high dwords of first 64 edge values == 0.
__device__ __forceinline__ void block_detect(const unsigned int* __restrict__ xraw,
    const unsigned int* __restrict__ eraw, int* f32, int* i64) {
  __shared__ int c_bf, c_nz;
  if (threadIdx.x == 0) { c_bf = 0; c_nz = 0; }
  __syncthreads();
  unsigned int d = xraw[threadIdx.x & 255];
  int e = (int)(((d & 0xffffu) >> 7) & 0xff);
  if (e >= 100 && e <= 140) atomicAdd(&c_bf, 1);
  if (eraw && threadIdx.x < 64 && eraw[2 * threadIdx.x + 1] != 0u) atomicAdd(&c_nz, 1);
  __syncthreads();
  *f32 = (c_bf < 150) ? 1 : 0;
  if (i64) *i64 = (c_nz == 0) ? 1 : 0;
}

struct WPtrs { const void* p[10]; };
static constexpr int WSEG[10] = {16384, 128, 8192, 64, 2048, 32, 512, 16, 160, 10};
static constexpr int WTOTAL   = 27546;
static constexpr int WOFF[10] = {0, 16384, 16512, 24704, 24768, 26816, 26848, 27360, 27376, 27536};

// blocks [0,BW): weights; [BW,BW+BB): batch; rest: edges + degree count.
__global__ __launch_bounds__(256) void cvt_we_kernel(
    const unsigned int* __restrict__ xraw, WPtrs wp, unsigned short* __restrict__ wc,
    const int* __restrict__ braw, int* __restrict__ b32,
    const int* __restrict__ eraw, int* __restrict__ src32, int* __restrict__ dst32,
    int* __restrict__ deg, int BW, int BB, int n, int E) {
  int f32, i64;
  block_detect(xraw, (const unsigned int*)eraw, &f32, &i64);
  const int bid = blockIdx.x;
  if (bid < BW) {
    int i = bid * 256 + threadIdx.x;
    if (i >= WTOTAL) return;
    int off = i, s = 0;
    #pragma unroll
    for (int t = 0; t < 10; ++t) {
      if (s == 0 && off >= WSEG[t]) { off -= WSEG[t]; } else if (s == 0) { s = t + 1; }
    }
    s -= 1;
    int soff = off;
    if ((s & 1) == 0 && s <= 6) {           // W1..W4 -> fragment-major
      int KB, FOUT;
      if (s == 0)      { KB = 4; FOUT = 128; }
      else if (s == 2) { KB = 4; FOUT = 64; }
      else if (s == 4) { KB = 2; FOUT = 32; }
      else             { KB = 1; FOUT = 16; }
      int j = off & 7, l = (off >> 3) & 63, f = off >> 9;
      int ct = f / KB, kb = f - ct * KB;
      int k = kb * 32 + ((l >> 4) << 3) + j;
      int nn = ct * 16 + (l & 15);
      soff = k * FOUT + nn;
    }
    const void* p = wp.p[s];
    wc[WOFF[s] + off] = f32 ? f2b(((const float*)p)[soff])
                            : ((const unsigned short*)p)[soff];
  } else if (bid < BW + BB) {
    int i = (bid - BW) * 256 + threadIdx.x;
    if (i < n) b32[i] = i64 ? braw[2 * i] : braw[i];
  } else {
    int e = (bid - BW - BB) * 256 + threadIdx.x;
    if (e >= E) return;
    int s, d;
    if (i64) { s = eraw[2 * e]; d = eraw[2 * (E + e)]; }
    else     { s = eraw[e];     d = eraw[E + e]; }
    src32[e] = s; dst32[e] = d;
    atomicAdd(&deg[d], 1);
  }
}

__device__ __forceinline__ int block_incl_scan(int v, int* wave_sums) {
  const int lane = threadIdx.x & 63;
  const int wv = threadIdx.x >> 6;
  int x = v;
  #pragma unroll
  for (int off = 1; off < 64; off <<= 1) {
    int y = __shfl_up(x, off, 64);
    if (lane >= off) x += y;
  }
  if (lane == 63) wave_sums[wv] = x;
  __syncthreads();
  int wbase = 0;
  for (int w = 0; w < wv; ++w) wbase += wave_sums[w];
  return x + wbase;
}

__global__ __launch_bounds__(256) void scan1_kernel(const int* __restrict__ deg,
    int* __restrict__ partials, int n) {
  __shared__ int ws[4];
  int i = blockIdx.x * 256 + threadIdx.x;
  int v = (i < n) ? deg[i] : 0;
  int incl = block_incl_scan(v, ws);
  if (threadIdx.x == 255) partials[blockIdx.x] = incl;
}

// block scan of deg + per-block reduce of partials[0..bid) -> final outputs
__global__ __launch_bounds__(256) void scan23_kernel(const int* __restrict__ deg,
    const int* __restrict__ partials, int* __restrict__ row_ptr, int* __restrict__ cursor,
    float* __restrict__ dinv, int n, int nb) {
  __shared__ int ws[4];
  __shared__ int s_red[4];
  __shared__ int s_base;
  int i = blockIdx.x * 256 + threadIdx.x;
  int v = (i < n) ? deg[i] : 0;
  int incl = block_incl_scan(v, ws);
  int pv = (threadIdx.x < blockIdx.x && threadIdx.x < nb) ? partials[threadIdx.x] : 0;
  #pragma unroll
  for (int off = 32; off; off >>= 1) pv += __shfl_xor(pv, off, 64);
  __syncthreads();
  if ((threadIdx.x & 63) == 0) s_red[threadIdx.x >> 6] = pv;
  __syncthreads();
  if (threadIdx.x == 0) s_base = s_red[0] + s_red[1] + s_red[2] + s_red[3];
  __syncthreads();
  int total = s_base + incl;
  if (i < n) {
    row_ptr[i + 1] = total;
    cursor[i] = total - v;
    dinv[i] = rsqrtf((float)v + 1.0f);
  }
  if (i == 0) row_ptr[0] = 0;
}

__global__ void fill_kernel(const int* __restrict__ src, const int* __restrict__ dst,
    int* __restrict__ cursor, const float* __restrict__ dinv,
    uint2* __restrict__ csr, int E) {
  int e = blockIdx.x * blockDim.x + threadIdx.x;
  if (e < E) {
    int s = src[e], d = dst[e];
    int pos = atomicAdd(&cursor[d], 1);
    uint2 v;
    v.x = (unsigned int)s;
    v.y = __float_as_uint(dinv[s] * dinv[d]);
    csr[pos] = v;
  }
}

// H = X @ W1 via MFMA; A-frags straight from raw x (fp32 or bf16, per-block
// detected, wave-uniform branch). B from fragment-major Wf (L2-hot). No LDS.
__global__ __launch_bounds__(256) void gemm1_kernel(const unsigned int* __restrict__ xraw,
    const unsigned short* __restrict__ Wf, unsigned short* __restrict__ H, int n) {
  int f32;
  block_detect(xraw, nullptr, &f32, nullptr);
  const int l = threadIdx.x & 63;
  const int r16 = l & 15, quad = l >> 4;
  const int m0 = (blockIdx.x * 4 + (threadIdx.x >> 6)) * 32;
  if (m0 >= n) return;
  bf8_t afrag[2][4];
  #pragma unroll
  for (int mt = 0; mt < 2; ++mt) {
    int node = m0 + mt * 16 + r16;
    int nc = node < n ? node : n - 1;
    if (f32) {
      const float* xp = (const float*)xraw + (size_t)nc * 128 + quad * 8;
      #pragma unroll
      for (int kb = 0; kb < 4; ++kb) {
        const float4* p4 = (const float4*)(xp + kb * 32);
        float4 u0 = p4[0], u1 = p4[1];
        bf8_t a;
        a[0] = (short)f2b(u0.x); a[1] = (short)f2b(u0.y);
        a[2] = (short)f2b(u0.z); a[3] = (short)f2b(u0.w);
        a[4] = (short)f2b(u1.x); a[5] = (short)f2b(u1.y);
        a[6] = (short)f2b(u1.z); a[7] = (short)f2b(u1.w);
        afrag[mt][kb] = a;
      }
    } else {
      const unsigned short* xp = (const unsigned short*)xraw + (size_t)nc * 128 + quad * 8;
      #pragma unroll
      for (int kb = 0; kb < 4; ++kb)
        afrag[mt][kb] = *(const bf8_t*)(xp + kb * 32);
    }
  }
  #pragma unroll
  for (int ct = 0; ct < 8; ++ct) {
    bf8_t bfrag[4];
    #pragma unroll
    for (int kb = 0; kb < 4; ++kb)
      bfrag[kb] = *(const bf8_t*)(Wf + ((ct * 4 + kb) * 64 + l) * 8);
    #pragma unroll
    for (int mt = 0; mt < 2; ++mt) {
      f4_t acc = {0.f, 0.f, 0.f, 0.f};
      #pragma unroll
      for (int kb = 0; kb < 4; ++kb)
        acc = __builtin_amdgcn_mfma_f32_16x16x32_bf16(afrag[mt][kb], bfrag[kb], acc, 0, 0, 0);
      #pragma unroll
      for (int r = 0; r < 4; ++r) {
        int node = m0 + mt * 16 + quad * 4 + r;
        if (node < n)
          H[(size_t)node * 128 + ct * 16 + r16] = f2b(acc[r]);
      }
    }
  }
}

// Fused: agg over Hin (FIN feats) -> LDS tile (128 nodes) -> MFMA with Wf
// (FIN x FOUT, fragment-major) -> Hout. Tile LDS padded +8 shorts/row:
// ds_read_b128 A-frags land 2-way bank aliased (free).
template<int FIN, int FOUT>
__global__ __launch_bounds__(256) void agg_gemm_kernel(
    const unsigned short* __restrict__ Hin,
    const int* __restrict__ row_ptr, const uint2* __restrict__ csr,
    const float* __restrict__ dinv, const unsigned short* __restrict__ bias,
    const unsigned short* __restrict__ Wf, unsigned short* __restrict__ Hout, int n) {
  constexpr int LPG = FIN / 8;
  constexpr int LD = FIN + 8;
  __shared__ unsigned short T[128 * LD];
  const int m0 = blockIdx.x * 128;
  const uint4* H4 = (const uint4*)Hin;
  for (int slot = threadIdx.x; slot < 128 * LPG; slot += 256) {
    int r = slot / LPG, l = slot - r * LPG;
    int g = m0 + r;
    uint4 o = {0u, 0u, 0u, 0u};
    if (g < n) {
      float di = dinv[g];
      float c0 = di * di;
      uint4 hv = H4[(size_t)g * LPG + l];
      float a0 = b2f(hv.x & 0xffffu) * c0, a1 = b2f(hv.x >> 16) * c0;
      float a2 = b2f(hv.y & 0xffffu) * c0, a3 = b2f(hv.y >> 16) * c0;
      float a4 = b2f(hv.z & 0xffffu) * c0, a5 = b2f(hv.z >> 16) * c0;
      float a6 = b2f(hv.w & 0xffffu) * c0, a7 = b2f(hv.w >> 16) * c0;
      const int e0 = row_ptr[g], e1 = row_ptr[g + 1];
      for (int base = e0; base < e1; base += LPG) {
        int cnt = e1 - base < LPG ? e1 - base : LPG;
        uint2 my = csr[(base + l < e1) ? (base + l) : (e1 - 1)];
        for (int j = 0; j < cnt; ++j) {
          int s = __shfl((int)my.x, j, LPG);
          float c = __uint_as_float(__shfl((int)my.y, j, LPG));
          uint4 v = H4[(size_t)s * LPG + l];
          a0 = fmaf(b2f(v.x & 0xffffu), c, a0); a1 = fmaf(b2f(v.x >> 16), c, a1);
          a2 = fmaf(b2f(v.y & 0xffffu), c, a2); a3 = fmaf(b2f(v.y >> 16), c, a3);
          a4 = fmaf(b2f(v.z & 0xffffu), c, a4); a5 = fmaf(b2f(v.z >> 16), c, a5);
          a6 = fmaf(b2f(v.w & 0xffffu), c, a6); a7 = fmaf(b2f(v.w >> 16), c, a7);
        }
      }
      uint4 bb = ((const uint4*)bias)[l];
      a0 += b2f(bb.x & 0xffffu); a1 += b2f(bb.x >> 16);
      a2 += b2f(bb.y & 0xffffu); a3 += b2f(bb.y >> 16);
      a4 += b2f(bb.z & 0xffffu); a5 += b2f(bb.z >> 16);
      a6 += b2f(bb.w & 0xffffu); a7 += b2f(bb.w >> 16);
      a0 = fmaxf(a0, 0.f); a1 = fmaxf(a1, 0.f); a2 = fmaxf(a2, 0.f); a3 = fmaxf(a3, 0.f);
      a4 = fmaxf(a4, 0.f); a5 = fmaxf(a5, 0.f); a6 = fmaxf(a6, 0.f); a7 = fmaxf(a7, 0.f);
      o.x = (unsigned int)f2b(a0) | ((unsigned int)f2b(a1) << 16);
      o.y = (unsigned int)f2b(a2) | ((unsigned int)f2b(a3) << 16);
      o.z = (unsigned int)f2b(a4) | ((unsigned int)f2b(a5) << 16);
      o.w = (unsigned int)f2b(a6) | ((unsigned int)f2b(a7) << 16);
    }
    *(uint4*)(&T[r * LD + l * 8]) = o;
  }
  __syncthreads();
  if (m0 >= n) return;
  // ---- MFMA phase ----
  constexpr int KB = FIN / 32;
  constexpr int CT = FOUT / 16;
  const int l = threadIdx.x & 63;
  const int r16 = l & 15, quad = l >> 4;
  const int w = threadIdx.x >> 6;
  bf8_t afrag[2][KB];
  #pragma unroll
  for (int mt = 0; mt < 2; ++mt) {
    int row = w * 32 + mt * 16 + r16;
    #pragma unroll
    for (int kb = 0; kb < KB; ++kb)
      afrag[mt][kb] = *(const bf8_t*)(&T[row * LD + quad * 8 + kb * 32]);
  }
  #pragma unroll
  for (int ct = 0; ct < CT; ++ct) {
    bf8_t bfrag[KB];
    #pragma unroll
    for (int kb = 0; kb < KB; ++kb)
      bfrag[kb] = *(const bf8_t*)(Wf + ((ct * KB + kb) * 64 + l) * 8);
    #pragma unroll
    for (int mt = 0; mt < 2; ++mt) {
      f4_t acc = {0.f, 0.f, 0.f, 0.f};
      #pragma unroll
      for (int kb = 0; kb < KB; ++kb)
        acc = __builtin_amdgcn_mfma_f32_16x16x32_bf16(afrag[mt][kb], bfrag[kb], acc, 0, 0, 0);
      #pragma unroll
      for (int r = 0; r < 4; ++r) {
        int node = m0 + w * 32 + mt * 16 + quad * 4 + r;
        if (node < n)
          Hout[(size_t)node * FOUT + ct * 16 + r16] = f2b(acc[r]);
      }
    }
  }
}

// Fused: agg over Hin (16 feats) + relu -> per-block LDS graph accumulate ->
// global atomics. 128 nodes/block, 2 lanes/node.
__global__ __launch_bounds__(256) void agg_pool_kernel(
    const unsigned short* __restrict__ Hin,
    const int* __restrict__ row_ptr, const uint2* __restrict__ csr,
    const float* __restrict__ dinv, const unsigned short* __restrict__ bias,
    const int* __restrict__ batch, float* __restrict__ pooled,
    float* __restrict__ cnt, int n) {
  __shared__ float acc[N_GRAPHS * 16];
  __shared__ float ccnt[N_GRAPHS];
  for (int i = threadIdx.x; i < N_GRAPHS * 16; i += 256) acc[i] = 0.f;
  if (threadIdx.x < N_GRAPHS) ccnt[threadIdx.x] = 0.f;
  __syncthreads();
  const int r = threadIdx.x >> 1, l = threadIdx.x & 1;
  const int g = blockIdx.x * 128 + r;
  if (g < n) {
    const uint4* H4 = (const uint4*)Hin;
    float di = dinv[g];
    float c0 = di * di;
    uint4 hv = H4[(size_t)g * 2 + l];
    float a0 = b2f(hv.x & 0xffffu) * c0, a1 = b2f(hv.x >> 16) * c0;
    float a2 = b2f(hv.y & 0xffffu) * c0, a3 = b2f(hv.y >> 16) * c0;
    float a4 = b2f(hv.z & 0xffffu) * c0, a5 = b2f(hv.z >> 16) * c0;
    float a6 = b2f(hv.w & 0xffffu) * c0, a7 = b2f(hv.w >> 16) * c0;
    const int e0 = row_ptr[g], e1 = row_ptr[g + 1];
    for (int base = e0; base < e1; base += 2) {
      int cnt2 = e1 - base < 2 ? e1 - base : 2;
      uint2 my = csr[(base + l < e1) ? (base + l) : (e1 - 1)];
      for (int j = 0; j < cnt2; ++j) {
        int s = __shfl((int)my.x, j, 2);
        float c = __uint_as_float(__shfl((int)my.y, j, 2));
        uint4 v = H4[(size_t)s * 2 + l];
        a0 = fmaf(b2f(v.x & 0xffffu), c, a0); a1 = fmaf(b2f(v.x >> 16), c, a1);
        a2 = fmaf(b2f(v.y & 0xffffu), c, a2); a3 = fmaf(b2f(v.y >> 16), c, a3);
        a4 = fmaf(b2f(v.z & 0xffffu), c, a4); a5 = fmaf(b2f(v.z >> 16), c, a5);
        a6 = fmaf(b2f(v.w & 0xffffu), c, a6); a7 = fmaf(b2f(v.w >> 16), c, a7);
      }
    }
    uint4 bb = ((const uint4*)bias)[l];
    a0 += b2f(bb.x & 0xffffu); a1 += b2f(bb.x >> 16);
    a2 += b2f(bb.y & 0xffffu); a3 += b2f(bb.y >> 16);
    a4 += b2f(bb.z & 0xffffu); a5 += b2f(bb.z >> 16);
    a6 += b2f(bb.w & 0xffffu); a7 += b2f(bb.w >> 16);
    a0 = fmaxf(a0, 0.f); a1 = fmaxf(a1, 0.f); a2 = fmaxf(a2, 0.f); a3 = fmaxf(a3, 0.f);
    a4 = fmaxf(a4, 0.f); a5 = fmaxf(a5, 0.f); a6 = fmaxf(a6, 0.f); a7 = fmaxf(a7, 0.f);
    int gb = batch[g];
    float* ap = &acc[gb * 16 + l * 8];
    atomicAdd(ap + 0, a0); atomicAdd(ap + 1, a1);
    atomicAdd(ap + 2, a2); atomicAdd(ap + 3, a3);
    atomicAdd(ap + 4, a4); atomicAdd(ap + 5, a5);
    atomicAdd(ap + 6, a6); atomicAdd(ap + 7, a7);
    if (l == 0) atomicAdd(&ccnt[gb], 1.f);
  }
  __syncthreads();
  for (int i = threadIdx.x; i < N_GRAPHS * 16; i += 256)
    if (acc[i] != 0.f) atomicAdd(&pooled[i], acc[i]);
  if (threadIdx.x < N_GRAPHS && ccnt[threadIdx.x] != 0.f)
    atomicAdd(&cnt[threadIdx.x], ccnt[threadIdx.x]);
}

__global__ __launch_bounds__(256) void final_kernel(const float* __restrict__ pooled,
    const float* __restrict__ cnt, const unsigned short* __restrict__ wc,
    void* __restrict__ out, const unsigned int* __restrict__ xraw) {
  int f32;
  block_detect(xraw, nullptr, &f32, nullptr);
  int id = blockIdx.x * 256 + threadIdx.x;
  if (id >= N_GRAPHS * N_CLASSES) return;
  const unsigned short* Wlin = wc + WOFF[8];
  const unsigned short* blin = wc + WOFF[9];
  int g = id / N_CLASSES, c = id - g * N_CLASSES;
  float inv = 1.0f / fmaxf(cnt[g], 1.0f);
  float a = b2f(blin[c]);
  #pragma unroll
  for (int f = 0; f < 16; ++f)
    a = fmaf(pooled[g * 16 + f] * inv, b2f(Wlin[f * N_CLASSES + c]), a);
  if (f32) ((float*)out)[id] = a;
  else     ((unsigned short*)out)[id] = f2b(a);
}

extern "C" void kernel_launch(void* const* d_in, const int* in_sizes, int n_in,
                              void* d_out, int out_size, void* d_ws, size_t ws_size,
                              hipStream_t stream) {
  const unsigned int* xraw = (const unsigned int*)d_in[0];
  const int* eraw          = (const int*)d_in[1];
  const int* braw          = (const int*)d_in[2];

  const int N = in_sizes[2];
  const int E = in_sizes[1] / 2;

  char* p = (char*)d_ws;
  auto alloc = [&](size_t bytes) -> void* {
    void* r = (void*)p;
    p += (bytes + 255) & ~(size_t)255;
    return r;
  };
  int*   deg      = (int*)  alloc((size_t)N * 4);
  int*   partials = (int*)  alloc(1024);
  int*   row_ptr  = (int*)  alloc((size_t)(N + 1) * 4);
  int*   cursor   = (int*)  alloc((size_t)N * 4);
  float* dinv     = (float*)alloc((size_t)N * 4);
  int*   src32    = (int*)  alloc((size_t)E * 4);
  int*   dst32    = (int*)  alloc((size_t)E * 4);
  int*   batch32  = (int*)  alloc((size_t)N * 4);
  uint2* csr      = (uint2*)alloc((size_t)E * 8);
  unsigned short* wcan  = (unsigned short*)alloc((size_t)WTOTAL * 2);
  unsigned short* hbufA = (unsigned short*)alloc((size_t)N * 128 * 2);
  unsigned short* hbufB = (unsigned short*)alloc((size_t)N * 64 * 2);
  float* pooled = (float*)alloc((N_GRAPHS * 16 + N_GRAPHS) * 4);
  float* cntf   = pooled + N_GRAPHS * 16;

  hipMemsetAsync(deg, 0, (size_t)N * 4, stream);
  hipMemsetAsync(pooled, 0, (N_GRAPHS * 16 + N_GRAPHS) * 4, stream);

  WPtrs wp;
  for (int i = 0; i < 10; ++i) wp.p[i] = d_in[3 + i];

  const int BW = (WTOTAL + 255) / 256;
  const int BB = (N + 255) / 256;
  const int BE = (E + 255) / 256;
  cvt_we_kernel<<<BW + BB + BE, 256, 0, stream>>>(xraw, wp, wcan, braw, batch32,
      eraw, src32, dst32, deg, BW, BB, N, E);

  const int nb = (N + 255) / 256;
  scan1_kernel<<<nb, 256, 0, stream>>>(deg, partials, N);
  scan23_kernel<<<nb, 256, 0, stream>>>(deg, partials, row_ptr, cursor, dinv, N, nb);
  fill_kernel<<<BE, 256, 0, stream>>>(src32, dst32, cursor, dinv, csr, E);

  const unsigned short* W1 = wcan + WOFF[0];
  const unsigned short* b1 = wcan + WOFF[1];
  const unsigned short* W2 = wcan + WOFF[2];
  const unsigned short* b2 = wcan + WOFF[3];
  const unsigned short* W3 = wcan + WOFF[4];
  const unsigned short* b3 = wcan + WOFF[5];
  const unsigned short* W4 = wcan + WOFF[6];
  const unsigned short* b4 = wcan + WOFF[7];

  const int tiles = (N + 127) / 128;

  gemm1_kernel<<<tiles, 256, 0, stream>>>(xraw, W1, hbufA, N);
  agg_gemm_kernel<128, 64><<<tiles, 256, 0, stream>>>(hbufA, row_ptr, csr, dinv, b1, W2, hbufB, N);
  agg_gemm_kernel<64, 32><<<tiles, 256, 0, stream>>>(hbufB, row_ptr, csr, dinv, b2, W3, hbufA, N);
  agg_gemm_kernel<32, 16><<<tiles, 256, 0, stream>>>(hbufA, row_ptr, csr, dinv, b3, W4, hbufB, N);
  agg_pool_kernel<<<tiles, 256, 0, stream>>>(hbufB, row_ptr, csr, dinv, b4, batch32, pooled, cntf, N);

  final_kernel<<<(N_GRAPHS * N_CLASSES + 255) / 256, 256, 0, stream>>>(pooled, cntf, wcan, d_out, xraw);
}

// Round 6
// 266.076 us; speedup vs baseline: 1.1829x; 1.1829x over previous
//
#include <hip/hip_runtime.h>
#include <hip/hip_bf16.h>

// GCN forward, MI355X. Round 6: de-fused agg/gemm (occupancy >> fusion),
// round-5 prep pipeline retained.
//   memset(deg), memset(pooled+cnt)
//   cvt_we  : W->bf16 canonical (W1..W4 fragment-major) | batch->i32 |
//             edges->i32 + degree count   (per-block inline dtype detect)
//   scan1, scan23 : hierarchical scan -> row_ptr / cursor / dinv
//   fill    : packed uint2 CSR (src, coef)
//   gemm1   : X @ W1 via MFMA straight from raw x (fp32 or bf16)
//   3x (agg<F> standalone [16B/lane gather, 32 waves/CU] -> gemm<FIN,FOUT>
//       [LDS-free, fragment-major W])
//   agg_pool: last-layer gather + relu -> LDS graph accumulate -> atomics
//   final   : 64x16 @ 16x10 linear, dtype-dispatched store
//
// Lesson R5: fused agg+MFMA tiles force grid=N/128 (~6 waves/CU) and expose
// full L3 gather latency; standalone agg at N/16 blocks runs at the 32-wave
// cap. Fusion saved ~25MB L2 traffic but cost ~40us of exposed latency.
//
// MFMA 16x16x32_bf16 layouts (verified): A[m=l&15][k=(l>>4)*8+j] (k-contig);
// B frag f at Wf[f*1024 + l*16..+16] = B[kb*32+(l>>4)*8+j][ct*16+(l&15)],
// f=ct*KB+kb; C/D col=l&15, row=(l>>4)*4+reg.

#define N_GRAPHS 64
#define N_CLASSES 10

typedef short bf8_t __attribute__((ext_vector_type(8)));
typedef float f4_t  __attribute__((ext_vector_type(4)));

__device__ __forceinline__ float b2f(unsigned int u) {
  return __uint_as_float(u << 16);
}
__device__ __forceinline__ unsigned short f2b(float f) {
  unsigned int x = __float_as_uint(f);
  x += 0x7fffu + ((x >> 16) & 1u);   // RNE (finite values only)
  return (unsigned short)(x >> 16);
}

// Per-block dtype detect; call with all 256 threads pre-divergence.
__device__ __forceinline__ void block_detect(const unsigned int* __restrict__ xraw,
    const unsigned int* __restrict__ eraw, int* f32, int* i64) {
  __shared__ int c_bf, c_nz;
  if (threadIdx.x == 0) { c_bf = 0; c_nz = 0; }
  __syncthreads();
  unsigned int d = xraw[threadIdx.x & 255];
  int e = (int)(((d & 0xffffu) >> 7) & 0xff);
  if (e >= 100 && e <= 140) atomicAdd(&c_bf, 1);
  if (eraw && threadIdx.x < 64 && eraw[2 * threadIdx.x + 1] != 0u) atomicAdd(&c_nz, 1);
  __syncthreads();
  *f32 = (c_bf < 150) ? 1 : 0;
  if (i64) *i64 = (c_nz == 0) ? 1 : 0;
}

struct WPtrs { const void* p[10]; };
static constexpr int WSEG[10] = {16384, 128, 8192, 64, 2048, 32, 512, 16, 160, 10};
static constexpr int WTOTAL   = 27546;
static constexpr int WOFF[10] = {0, 16384, 16512, 24704, 24768, 26816, 26848, 27360, 27376, 27536};

__global__ __launch_bounds__(256) void cvt_we_kernel(
    const unsigned int* __restrict__ xraw, WPtrs wp, unsigned short* __restrict__ wc,
    const int* __restrict__ braw, int* __restrict__ b32,
    const int* __restrict__ eraw, int* __restrict__ src32, int* __restrict__ dst32,
    int* __restrict__ deg, int BW, int BB, int n, int E) {
  int f32, i64;
  block_detect(xraw, (const unsigned int*)eraw, &f32, &i64);
  const int bid = blockIdx.x;
  if (bid < BW) {
    int i = bid * 256 + threadIdx.x;
    if (i >= WTOTAL) return;
    int off = i, s = 0;
    #pragma unroll
    for (int t = 0; t < 10; ++t) {
      if (s == 0 && off >= WSEG[t]) { off -= WSEG[t]; } else if (s == 0) { s = t + 1; }
    }
    s -= 1;
    int soff = off;
    if ((s & 1) == 0 && s <= 6) {           // W1..W4 -> fragment-major
      int KB, FOUT;
      if (s == 0)      { KB = 4; FOUT = 128; }
      else if (s == 2) { KB = 4; FOUT = 64; }
      else if (s == 4) { KB = 2; FOUT = 32; }
      else             { KB = 1; FOUT = 16; }
      int j = off & 7, l = (off >> 3) & 63, f = off >> 9;
      int ct = f / KB, kb = f - ct * KB;
      int k = kb * 32 + ((l >> 4) << 3) + j;
      int nn = ct * 16 + (l & 15);
      soff = k * FOUT + nn;
    }
    const void* p = wp.p[s];
    wc[WOFF[s] + off] = f32 ? f2b(((const float*)p)[soff])
                            : ((const unsigned short*)p)[soff];
  } else if (bid < BW + BB) {
    int i = (bid - BW) * 256 + threadIdx.x;
    if (i < n) b32[i] = i64 ? braw[2 * i] : braw[i];
  } else {
    int e = (bid - BW - BB) * 256 + threadIdx.x;
    if (e >= E) return;
    int s, d;
    if (i64) { s = eraw[2 * e]; d = eraw[2 * (E + e)]; }
    else     { s = eraw[e];     d = eraw[E + e]; }
    src32[e] = s; dst32[e] = d;
    atomicAdd(&deg[d], 1);
  }
}

__device__ __forceinline__ int block_incl_scan(int v, int* wave_sums) {
  const int lane = threadIdx.x & 63;
  const int wv = threadIdx.x >> 6;
  int x = v;
  #pragma unroll
  for (int off = 1; off < 64; off <<= 1) {
    int y = __shfl_up(x, off, 64);
    if (lane >= off) x += y;
  }
  if (lane == 63) wave_sums[wv] = x;
  __syncthreads();
  int wbase = 0;
  for (int w = 0; w < wv; ++w) wbase += wave_sums[w];
  return x + wbase;
}

__global__ __launch_bounds__(256) void scan1_kernel(const int* __restrict__ deg,
    int* __restrict__ partials, int n) {
  __shared__ int ws[4];
  int i = blockIdx.x * 256 + threadIdx.x;
  int v = (i < n) ? deg[i] : 0;
  int incl = block_incl_scan(v, ws);
  if (threadIdx.x == 255) partials[blockIdx.x] = incl;
}

__global__ __launch_bounds__(256) void scan23_kernel(const int* __restrict__ deg,
    const int* __restrict__ partials, int* __restrict__ row_ptr, int* __restrict__ cursor,
    float* __restrict__ dinv, int n, int nb) {
  __shared__ int ws[4];
  __shared__ int s_red[4];
  __shared__ int s_base;
  int i = blockIdx.x * 256 + threadIdx.x;
  int v = (i < n) ? deg[i] : 0;
  int incl = block_incl_scan(v, ws);
  int pv = (threadIdx.x < blockIdx.x && threadIdx.x < nb) ? partials[threadIdx.x] : 0;
  #pragma unroll
  for (int off = 32; off; off >>= 1) pv += __shfl_xor(pv, off, 64);
  __syncthreads();
  if ((threadIdx.x & 63) == 0) s_red[threadIdx.x >> 6] = pv;
  __syncthreads();
  if (threadIdx.x == 0) s_base = s_red[0] + s_red[1] + s_red[2] + s_red[3];
  __syncthreads();
  int total = s_base + incl;
  if (i < n) {
    row_ptr[i + 1] = total;
    cursor[i] = total - v;
    dinv[i] = rsqrtf((float)v + 1.0f);
  }
  if (i == 0) row_ptr[0] = 0;
}

__global__ void fill_kernel(const int* __restrict__ src, const int* __restrict__ dst,
    int* __restrict__ cursor, const float* __restrict__ dinv,
    uint2* __restrict__ csr, int E) {
  int e = blockIdx.x * blockDim.x + threadIdx.x;
  if (e < E) {
    int s = src[e], d = dst[e];
    int pos = atomicAdd(&cursor[d], 1);
    uint2 v;
    v.x = (unsigned int)s;
    v.y = __float_as_uint(dinv[s] * dinv[d]);
    csr[pos] = v;
  }
}

// H = X @ W1 via MFMA; A-frags straight from raw x (fp32 or bf16).
__global__ __launch_bounds__(256) void gemm1_kernel(const unsigned int* __restrict__ xraw,
    const unsigned short* __restrict__ Wf, unsigned short* __restrict__ H, int n) {
  int f32;
  block_detect(xraw, nullptr, &f32, nullptr);
  const int l = threadIdx.x & 63;
  const int r16 = l & 15, quad = l >> 4;
  const int m0 = (blockIdx.x * 4 + (threadIdx.x >> 6)) * 32;
  if (m0 >= n) return;
  bf8_t afrag[2][4];
  #pragma unroll
  for (int mt = 0; mt < 2; ++mt) {
    int node = m0 + mt * 16 + r16;
    int nc = node < n ? node : n - 1;
    if (f32) {
      const float* xp = (const float*)xraw + (size_t)nc * 128 + quad * 8;
      #pragma unroll
      for (int kb = 0; kb < 4; ++kb) {
        const float4* p4 = (const float4*)(xp + kb * 32);
        float4 u0 = p4[0], u1 = p4[1];
        bf8_t a;
        a[0] = (short)f2b(u0.x); a[1] = (short)f2b(u0.y);
        a[2] = (short)f2b(u0.z); a[3] = (short)f2b(u0.w);
        a[4] = (short)f2b(u1.x); a[5] = (short)f2b(u1.y);
        a[6] = (short)f2b(u1.z); a[7] = (short)f2b(u1.w);
        afrag[mt][kb] = a;
      }
    } else {
      const unsigned short* xp = (const unsigned short*)xraw + (size_t)nc * 128 + quad * 8;
      #pragma unroll
      for (int kb = 0; kb < 4; ++kb)
        afrag[mt][kb] = *(const bf8_t*)(xp + kb * 32);
    }
  }
  #pragma unroll
  for (int ct = 0; ct < 8; ++ct) {
    bf8_t bfrag[4];
    #pragma unroll
    for (int kb = 0; kb < 4; ++kb)
      bfrag[kb] = *(const bf8_t*)(Wf + ((ct * 4 + kb) * 64 + l) * 8);
    #pragma unroll
    for (int mt = 0; mt < 2; ++mt) {
      f4_t acc = {0.f, 0.f, 0.f, 0.f};
      #pragma unroll
      for (int kb = 0; kb < 4; ++kb)
        acc = __builtin_amdgcn_mfma_f32_16x16x32_bf16(afrag[mt][kb], bfrag[kb], acc, 0, 0, 0);
      #pragma unroll
      for (int r = 0; r < 4; ++r) {
        int node = m0 + mt * 16 + quad * 4 + r;
        if (node < n)
          H[(size_t)node * 128 + ct * 16 + r16] = f2b(acc[r]);
      }
    }
  }
}

// Standalone GEMM: H[n,FOUT] = X[n,FIN] @ Wf (fragment-major). No LDS.
template<int FIN, int FOUT>
__global__ __launch_bounds__(256) void mfma_gemm_kernel(const unsigned short* __restrict__ X,
    const unsigned short* __restrict__ Wf, unsigned short* __restrict__ H, int n) {
  constexpr int KB = FIN / 32;
  constexpr int CT = FOUT / 16;
  const int l = threadIdx.x & 63;
  const int r16 = l & 15, quad = l >> 4;
  const int m0 = (blockIdx.x * 4 + (threadIdx.x >> 6)) * 32;
  if (m0 >= n) return;
  bf8_t afrag[2][KB];
  #pragma unroll
  for (int mt = 0; mt < 2; ++mt) {
    int node = m0 + mt * 16 + r16;
    int nc = node < n ? node : n - 1;
    const unsigned short* xp = X + (size_t)nc * FIN + quad * 8;
    #pragma unroll
    for (int kb = 0; kb < KB; ++kb)
      afrag[mt][kb] = *(const bf8_t*)(xp + kb * 32);
  }
  #pragma unroll
  for (int ct = 0; ct < CT; ++ct) {
    bf8_t bfrag[KB];
    #pragma unroll
    for (int kb = 0; kb < KB; ++kb)
      bfrag[kb] = *(const bf8_t*)(Wf + ((ct * KB + kb) * 64 + l) * 8);
    #pragma unroll
    for (int mt = 0; mt < 2; ++mt) {
      f4_t acc = {0.f, 0.f, 0.f, 0.f};
      #pragma unroll
      for (int kb = 0; kb < KB; ++kb)
        acc = __builtin_amdgcn_mfma_f32_16x16x32_bf16(afrag[mt][kb], bfrag[kb], acc, 0, 0, 0);
      #pragma unroll
      for (int r = 0; r < 4; ++r) {
        int node = m0 + mt * 16 + quad * 4 + r;
        if (node < n)
          H[(size_t)node * FOUT + ct * 16 + r16] = f2b(acc[r]);
      }
    }
  }
}

// Standalone agg: OUT[g,:] = relu(sum coef*H[src] + dinv^2*H[g] + bias).
// F/8 lanes per node, 16B/lane, shfl-broadcast CSR. Max occupancy.
template<int F>
__global__ __launch_bounds__(256) void agg_kernel(const unsigned short* __restrict__ H,
    const int* __restrict__ row_ptr, const uint2* __restrict__ csr,
    const float* __restrict__ dinv,
    const unsigned short* __restrict__ bias, unsigned short* __restrict__ OUT, int n) {
  constexpr int LPG = F / 8;
  constexpr int GPB = 256 / LPG;
  const int g = blockIdx.x * GPB + threadIdx.x / LPG;
  const int l = threadIdx.x % LPG;
  if (g >= n) return;
  const uint4* H4 = (const uint4*)H;
  float di = dinv[g];
  float c0 = di * di;
  uint4 hv = H4[(size_t)g * LPG + l];
  float a0 = b2f(hv.x & 0xffffu) * c0, a1 = b2f(hv.x >> 16) * c0;
  float a2 = b2f(hv.y & 0xffffu) * c0, a3 = b2f(hv.y >> 16) * c0;
  float a4 = b2f(hv.z & 0xffffu) * c0, a5 = b2f(hv.z >> 16) * c0;
  float a6 = b2f(hv.w & 0xffffu) * c0, a7 = b2f(hv.w >> 16) * c0;
  const int e0 = row_ptr[g], e1 = row_ptr[g + 1];
  for (int base = e0; base < e1; base += LPG) {
    int cnt = e1 - base < LPG ? e1 - base : LPG;
    uint2 my = csr[(base + l < e1) ? (base + l) : (e1 - 1)];
    for (int j = 0; j < cnt; ++j) {
      int s = __shfl((int)my.x, j, LPG);
      float c = __uint_as_float(__shfl((int)my.y, j, LPG));
      uint4 v = H4[(size_t)s * LPG + l];
      a0 = fmaf(b2f(v.x & 0xffffu), c, a0); a1 = fmaf(b2f(v.x >> 16), c, a1);
      a2 = fmaf(b2f(v.y & 0xffffu), c, a2); a3 = fmaf(b2f(v.y >> 16), c, a3);
      a4 = fmaf(b2f(v.z & 0xffffu), c, a4); a5 = fmaf(b2f(v.z >> 16), c, a5);
      a6 = fmaf(b2f(v.w & 0xffffu), c, a6); a7 = fmaf(b2f(v.w >> 16), c, a7);
    }
  }
  uint4 bb = ((const uint4*)bias)[l];
  a0 += b2f(bb.x & 0xffffu); a1 += b2f(bb.x >> 16);
  a2 += b2f(bb.y & 0xffffu); a3 += b2f(bb.y >> 16);
  a4 += b2f(bb.z & 0xffffu); a5 += b2f(bb.z >> 16);
  a6 += b2f(bb.w & 0xffffu); a7 += b2f(bb.w >> 16);
  a0 = fmaxf(a0, 0.f); a1 = fmaxf(a1, 0.f); a2 = fmaxf(a2, 0.f); a3 = fmaxf(a3, 0.f);
  a4 = fmaxf(a4, 0.f); a5 = fmaxf(a5, 0.f); a6 = fmaxf(a6, 0.f); a7 = fmaxf(a7, 0.f);
  uint4 o;
  o.x = (unsigned int)f2b(a0) | ((unsigned int)f2b(a1) << 16);
  o.y = (unsigned int)f2b(a2) | ((unsigned int)f2b(a3) << 16);
  o.z = (unsigned int)f2b(a4) | ((unsigned int)f2b(a5) << 16);
  o.w = (unsigned int)f2b(a6) | ((unsigned int)f2b(a7) << 16);
  ((uint4*)OUT)[(size_t)g * LPG + l] = o;
}

// Fused last-layer agg + mean-pool. 128 nodes/block, 2 lanes/node.
__global__ __launch_bounds__(256) void agg_pool_kernel(
    const unsigned short* __restrict__ Hin,
    const int* __restrict__ row_ptr, const uint2* __restrict__ csr,
    const float* __restrict__ dinv, const unsigned short* __restrict__ bias,
    const int* __restrict__ batch, float* __restrict__ pooled,
    float* __restrict__ cnt, int n) {
  __shared__ float acc[N_GRAPHS * 16];
  __shared__ float ccnt[N_GRAPHS];
  for (int i = threadIdx.x; i < N_GRAPHS * 16; i += 256) acc[i] = 0.f;
  if (threadIdx.x < N_GRAPHS) ccnt[threadIdx.x] = 0.f;
  __syncthreads();
  const int r = threadIdx.x >> 1, l = threadIdx.x & 1;
  const int g = blockIdx.x * 128 + r;
  if (g < n) {
    const uint4* H4 = (const uint4*)Hin;
    float di = dinv[g];
    float c0 = di * di;
    uint4 hv = H4[(size_t)g * 2 + l];
    float a0 = b2f(hv.x & 0xffffu) * c0, a1 = b2f(hv.x >> 16) * c0;
    float a2 = b2f(hv.y & 0xffffu) * c0, a3 = b2f(hv.y >> 16) * c0;
    float a4 = b2f(hv.z & 0xffffu) * c0, a5 = b2f(hv.z >> 16) * c0;
    float a6 = b2f(hv.w & 0xffffu) * c0, a7 = b2f(hv.w >> 16) * c0;
    const int e0 = row_ptr[g], e1 = row_ptr[g + 1];
    for (int base = e0; base < e1; base += 2) {
      int cnt2 = e1 - base < 2 ? e1 - base : 2;
      uint2 my = csr[(base + l < e1) ? (base + l) : (e1 - 1)];
      for (int j = 0; j < cnt2; ++j) {
        int s = __shfl((int)my.x, j, 2);
        float c = __uint_as_float(__shfl((int)my.y, j, 2));
        uint4 v = H4[(size_t)s * 2 + l];
        a0 = fmaf(b2f(v.x & 0xffffu), c, a0); a1 = fmaf(b2f(v.x >> 16), c, a1);
        a2 = fmaf(b2f(v.y & 0xffffu), c, a2); a3 = fmaf(b2f(v.y >> 16), c, a3);
        a4 = fmaf(b2f(v.z & 0xffffu), c, a4); a5 = fmaf(b2f(v.z >> 16), c, a5);
        a6 = fmaf(b2f(v.w & 0xffffu), c, a6); a7 = fmaf(b2f(v.w >> 16), c, a7);
      }
    }
    uint4 bb = ((const uint4*)bias)[l];
    a0 += b2f(bb.x & 0xffffu); a1 += b2f(bb.x >> 16);
    a2 += b2f(bb.y & 0xffffu); a3 += b2f(bb.y >> 16);
    a4 += b2f(bb.z & 0xffffu); a5 += b2f(bb.z >> 16);
    a6 += b2f(bb.w & 0xffffu); a7 += b2f(bb.w >> 16);
    a0 = fmaxf(a0, 0.f); a1 = fmaxf(a1, 0.f); a2 = fmaxf(a2, 0.f); a3 = fmaxf(a3, 0.f);
    a4 = fmaxf(a4, 0.f); a5 = fmaxf(a5, 0.f); a6 = fmaxf(a6, 0.f); a7 = fmaxf(a7, 0.f);
    int gb = batch[g];
    float* ap = &acc[gb * 16 + l * 8];
    atomicAdd(ap + 0, a0); atomicAdd(ap + 1, a1);
    atomicAdd(ap + 2, a2); atomicAdd(ap + 3, a3);
    atomicAdd(ap + 4, a4); atomicAdd(ap + 5, a5);
    atomicAdd(ap + 6, a6); atomicAdd(ap + 7, a7);
    if (l == 0) atomicAdd(&ccnt[gb], 1.f);
  }
  __syncthreads();
  for (int i = threadIdx.x; i < N_GRAPHS * 16; i += 256)
    if (acc[i] != 0.f) atomicAdd(&pooled[i], acc[i]);
  if (threadIdx.x < N_GRAPHS && ccnt[threadIdx.x] != 0.f)
    atomicAdd(&cnt[threadIdx.x], ccnt[threadIdx.x]);
}

__global__ __launch_bounds__(256) void final_kernel(const float* __restrict__ pooled,
    const float* __restrict__ cnt, const unsigned short* __restrict__ wc,
    void* __restrict__ out, const unsigned int* __restrict__ xraw) {
  int f32;
  block_detect(xraw, nullptr, &f32, nullptr);
  int id = blockIdx.x * 256 + threadIdx.x;
  if (id >= N_GRAPHS * N_CLASSES) return;
  const unsigned short* Wlin = wc + WOFF[8];
  const unsigned short* blin = wc + WOFF[9];
  int g = id / N_CLASSES, c = id - g * N_CLASSES;
  float inv = 1.0f / fmaxf(cnt[g], 1.0f);
  float a = b2f(blin[c]);
  #pragma unroll
  for (int f = 0; f < 16; ++f)
    a = fmaf(pooled[g * 16 + f] * inv, b2f(Wlin[f * N_CLASSES + c]), a);
  if (f32) ((float*)out)[id] = a;
  else     ((unsigned short*)out)[id] = f2b(a);
}

extern "C" void kernel_launch(void* const* d_in, const int* in_sizes, int n_in,
                              void* d_out, int out_size, void* d_ws, size_t ws_size,
                              hipStream_t stream) {
  const unsigned int* xraw = (const unsigned int*)d_in[0];
  const int* eraw          = (const int*)d_in[1];
  const int* braw          = (const int*)d_in[2];

  const int N = in_sizes[2];
  const int E = in_sizes[1] / 2;

  char* p = (char*)d_ws;
  auto alloc = [&](size_t bytes) -> void* {
    void* r = (void*)p;
    p += (bytes + 255) & ~(size_t)255;
    return r;
  };
  int*   deg      = (int*)  alloc((size_t)N * 4);
  int*   partials = (int*)  alloc(1024);
  int*   row_ptr  = (int*)  alloc((size_t)(N + 1) * 4);
  int*   cursor   = (int*)  alloc((size_t)N * 4);
  float* dinv     = (float*)alloc((size_t)N * 4);
  int*   src32    = (int*)  alloc((size_t)E * 4);
  int*   dst32    = (int*)  alloc((size_t)E * 4);
  int*   batch32  = (int*)  alloc((size_t)N * 4);
  uint2* csr      = (uint2*)alloc((size_t)E * 8);
  unsigned short* wcan  = (unsigned short*)alloc((size_t)WTOTAL * 2);
  unsigned short* hbufA = (unsigned short*)alloc((size_t)N * 128 * 2);
  unsigned short* hbufB = (unsigned short*)alloc((size_t)N * 128 * 2);
  float* pooled = (float*)alloc((N_GRAPHS * 16 + N_GRAPHS) * 4);
  float* cntf   = pooled + N_GRAPHS * 16;

  hipMemsetAsync(deg, 0, (size_t)N * 4, stream);
  hipMemsetAsync(pooled, 0, (N_GRAPHS * 16 + N_GRAPHS) * 4, stream);

  WPtrs wp;
  for (int i = 0; i < 10; ++i) wp.p[i] = d_in[3 + i];

  const int BW = (WTOTAL + 255) / 256;
  const int BB = (N + 255) / 256;
  const int BE = (E + 255) / 256;
  cvt_we_kernel<<<BW + BB + BE, 256, 0, stream>>>(xraw, wp, wcan, braw, batch32,
      eraw, src32, dst32, deg, BW, BB, N, E);

  const int nb = (N + 255) / 256;
  scan1_kernel<<<nb, 256, 0, stream>>>(deg, partials, N);
  scan23_kernel<<<nb, 256, 0, stream>>>(deg, partials, row_ptr, cursor, dinv, N, nb);
  fill_kernel<<<BE, 256, 0, stream>>>(src32, dst32, cursor, dinv, csr, E);

  const unsigned short* W1 = wcan + WOFF[0];
  const unsigned short* b1 = wcan + WOFF[1];
  const unsigned short* W2 = wcan + WOFF[2];
  const unsigned short* b2 = wcan + WOFF[3];
  const unsigned short* W3 = wcan + WOFF[4];
  const unsigned short* b3 = wcan + WOFF[5];
  const unsigned short* W4 = wcan + WOFF[6];
  const unsigned short* b4 = wcan + WOFF[7];

  const int gblocks = ((N + 31) / 32 + 3) / 4;
  const int tiles128 = (N + 127) / 128;

  gemm1_kernel<<<tiles128 * 4 / 4 * 4 / 4, 256, 0, stream>>>(xraw, W1, hbufA, N);  // = tiles128? use gblocks
  // (gblocks == ceil(ceil(N/32)/4) == ceil(N/128) == tiles128)
  agg_kernel<128><<<(N + 15) / 16, 256, 0, stream>>>(hbufA, row_ptr, csr, dinv, b1, hbufB, N);
  mfma_gemm_kernel<128, 64><<<gblocks, 256, 0, stream>>>(hbufB, W2, hbufA, N);
  agg_kernel<64><<<(N + 31) / 32, 256, 0, stream>>>(hbufA, row_ptr, csr, dinv, b2, hbufB, N);
  mfma_gemm_kernel<64, 32><<<gblocks, 256, 0, stream>>>(hbufB, W3, hbufA, N);
  agg_kernel<32><<<(N + 63) / 64, 256, 0, stream>>>(hbufA, row_ptr, csr, dinv, b3, hbufB, N);
  mfma_gemm_kernel<32, 16><<<gblocks, 256, 0, stream>>>(hbufB, W4, hbufA, N);
  agg_pool_kernel<<<tiles128, 256, 0, stream>>>(hbufA, row_ptr, csr, dinv, b4, batch32, pooled, cntf, N);

  final_kernel<<<(N_GRAPHS * N_CLASSES + 255) / 256, 256, 0, stream>>>(pooled, cntf, wcan, d_out, xraw);
}